// Round 7
// baseline (66.698 us; speedup 1.0000x reference)
//
#include <hip/hip_runtime.h>

#define BDIM 8192
#define DDIM 256
#define NSLOTS 512

typedef __bf16 bf16x8 __attribute__((ext_vector_type(8)));
typedef float f32x4 __attribute__((ext_vector_type(4)));
typedef unsigned short u16x4 __attribute__((ext_vector_type(4)));

#define MEMF() asm volatile("" ::: "memory")
#define BARR()                       \
  do {                               \
    MEMF();                          \
    __builtin_amdgcn_s_barrier();    \
    MEMF();                          \
  } while (0)
#define VMW(n) asm volatile("s_waitcnt vmcnt(" #n ")" ::: "memory")

__device__ inline unsigned short f2bf(float f) {
  unsigned u = __float_as_uint(f);
  u += 0x7FFFu + ((u >> 16) & 1u);  // round-to-nearest-even
  return (unsigned short)(u >> 16);
}
__device__ inline float bf2f(unsigned short h) {
  return __uint_as_float(((unsigned)h) << 16);
}

// Direct global->LDS DMA, 16B/lane. LDS operand = wave-uniform base; HW
// scatters lane*16. Global source is per-lane (carries the swizzle).
__device__ inline void gload_lds16(const void* g, void* l) {
  __builtin_amdgcn_global_load_lds(
      (const __attribute__((address_space(1))) void*)g,
      (__attribute__((address_space(3))) void*)l, 16, 0, 0);
}

// ---------------------------------------------------------------------------
// Kernel 1: normalize rows and convert to bf16, once. One wave per row.
// Block 0 additionally zeroes the reduction slots.
// ---------------------------------------------------------------------------
__global__ __launch_bounds__(256) void norm_convert_kernel(
    const float* __restrict__ t, const float* __restrict__ v,
    unsigned short* __restrict__ tn, unsigned short* __restrict__ vn,
    float* __restrict__ slots) {
  int wid = threadIdx.x >> 6, lane = threadIdx.x & 63;
  if (blockIdx.x == 0) {
    slots[threadIdx.x] = 0.0f;
    slots[threadIdx.x + 256] = 0.0f;
  }
  int row = blockIdx.x * 4 + wid;
  const float* src;
  unsigned short* dst;
  if (row < BDIM) {
    src = t + (size_t)row * DDIM;
    dst = tn + (size_t)row * DDIM;
  } else {
    int r = row - BDIM;
    src = v + (size_t)r * DDIM;
    dst = vn + (size_t)r * DDIM;
  }
  float4 x = reinterpret_cast<const float4*>(src)[lane];
  float ss = x.x * x.x + x.y * x.y + x.z * x.z + x.w * x.w;
  #pragma unroll
  for (int off = 1; off < 64; off <<= 1) ss += __shfl_xor(ss, off, 64);
  float sc = 1.0f / fmaxf(sqrtf(ss), 1e-12f);
  u16x4 w;
  w[0] = f2bf(x.x * sc); w[1] = f2bf(x.y * sc);
  w[2] = f2bf(x.z * sc); w[3] = f2bf(x.w * sc);
  reinterpret_cast<u16x4*>(dst)[lane] = w;
}

// ---------------------------------------------------------------------------
// Kernel 2: 256x256-tile bf16 GEMM, *4 waves* (2Mx2N), wave-tile 128x128,
// BK=64, one barrier per K-tile.
//
// ROUND-7 CHANGE: wave-tile 128x64 -> 128x128. LDS-read volume per FLOP
// drops 1.5x: per K-tile per wave, reads = A 16KB + B 16KB = 32 ds_read_b128
// for 2x the MFMA work (128 vs 64). Per block: LDS reads 786->524KB (~6.2k
// cyc) vs MFMA ~9.9k cyc -> MFMA-issue-bound. Cost: acc[8][8] = 256 VGPR ->
// 1 wave/SIMD (launch_bounds(256,1); ~390 VGPR total, below the 450-no-spill
// line). Each SIMD's matrix pipe is fed by one wave with 64 independent
// accumulators (issue-limited, no dependency stalls). DMA staging regions
// now take 2 calls each (256 thr x 16B = half of a 64x64 region).
//
// Schedule (round-5): issue-early all 16 prefetch DMAs into the dead buffer,
// straight-line reads+MFMA (compiler emits counted lgkmcnt), VMW(0)+BARR
// only at the tile boundary (residual-only wait).
// 2D panel-rectangle XCD swizzle (round-6). LDS XOR swizzle (involution):
// granule' = granule ^ (row&7) on global source + ds_read address.
// ---------------------------------------------------------------------------
__global__ __launch_bounds__(256, 1) void loss_kernel(
    const unsigned short* __restrict__ tn,
    const unsigned short* __restrict__ vn, float* __restrict__ slots) {
  __shared__ unsigned short Asb[2][16384];  // [buf][256 rows][64 cols]
  __shared__ unsigned short Bsb[2][16384];
  __shared__ float rbuf[4];

  const int tid = threadIdx.x;
  const int lane = tid & 63;
  const int wid = tid >> 6;
  const int l15 = lane & 15;
  const int l4 = lane >> 4;
  const int wm = wid >> 1;  // 0..1: wave's 128-row half
  const int wn = wid & 1;   // 0..1: wave's 128-col half

  // 2D panel-rectangle XCD swizzle (1024 blocks, 8 XCDs).
  const int flat = blockIdx.x;
  const int xcd = flat & 7;
  const int s = flat >> 3;   // 0..127 within XCD
  const int r = s >> 5;      // round 0..3 (32 CUs/XCD)
  const int p = s & 31;      // position in the 4x8 rectangle
  const int rowp = (xcd >> 2) * 16 + r * 4 + (p >> 3);  // 0..31
  const int colp = (xcd & 3) * 8 + (p & 7);             // 0..31
  const int rowBase = rowp * 256;
  const int colBase = colp * 256;

  // Staging: one region = 64 rows x 64 cols (8KB); 256 threads x 16B = 4KB
  // -> 2 DMA calls per region (32-row halves). row = h*32 + (tid>>3),
  // granule = tid&7, source granule pre-swizzled with row&7 = (tid>>3)&7.
  const int sg = (tid & 7) ^ ((tid >> 3) & 7);
  const unsigned short* gAsrc =
      tn + (size_t)(rowBase + (tid >> 3)) * DDIM + sg * 8;
  const unsigned short* gBsrc =
      vn + (size_t)(colBase + (tid >> 3)) * DDIM + sg * 8;
  const int ldsW = wid * 512;  // shorts; wave-uniform base in a 2048 half

  auto stA = [&](int ob, int rg, int kt) {
    #pragma unroll
    for (int h = 0; h < 2; ++h)
      gload_lds16(gAsrc + (size_t)(rg * 64 + h * 32) * DDIM + kt * 64,
                  &Asb[ob][rg * 4096 + h * 2048 + ldsW]);
  };
  auto stB = [&](int ob, int rg, int kt) {
    #pragma unroll
    for (int h = 0; h < 2; ++h)
      gload_lds16(gBsrc + (size_t)(rg * 64 + h * 32) * DDIM + kt * 64,
                  &Bsb[ob][rg * 4096 + h * 2048 + ldsW]);
  };

  f32x4 acc[8][8];
  #pragma unroll
  for (int i = 0; i < 8; ++i)
    #pragma unroll
    for (int j = 0; j < 8; ++j) acc[i][j] = (f32x4)(0.0f);

  // Prologue: stage tile 0 into buf0, drain, barrier.
  #pragma unroll
  for (int rg = 0; rg < 4; ++rg) stB(0, rg, 0);
  #pragma unroll
  for (int rg = 0; rg < 4; ++rg) stA(0, rg, 0);
  VMW(0);
  BARR();

  #pragma unroll
  for (int t = 0; t < 4; ++t) {  // K-tiles (K=256, BK=64)
    const int cur = t & 1, ob = cur ^ 1, kt = t + 1;
    // Issue-early: all 16 prefetch DMAs for tile t+1 (dead buffer).
    if (t < 3) {
      #pragma unroll
      for (int rg = 0; rg < 4; ++rg) stB(ob, rg, kt);
      #pragma unroll
      for (int rg = 0; rg < 4; ++rg) stA(ob, rg, kt);
    }
    // 32 ds_read_b128 (A 16, B 16), then 128 MFMA. Counted lgkmcnt lets
    // the first MFMAs start while the B kk=1 reads drain.
    bf16x8 af[8][2], bv[8][2];
    #pragma unroll
    for (int mm = 0; mm < 8; ++mm) {
      const int row = wm * 128 + mm * 16 + l15;  // row&7 == l15&7
      #pragma unroll
      for (int kk = 0; kk < 2; ++kk) {
        const int gg = (kk * 4 + l4) ^ (l15 & 7);
        af[mm][kk] =
            *reinterpret_cast<const bf16x8*>(&Asb[cur][row * 64 + gg * 8]);
      }
    }
    #pragma unroll
    for (int nn = 0; nn < 8; ++nn) {
      const int row = wn * 128 + nn * 16 + l15;
      #pragma unroll
      for (int kk = 0; kk < 2; ++kk) {
        const int gg = (kk * 4 + l4) ^ (l15 & 7);
        bv[nn][kk] =
            *reinterpret_cast<const bf16x8*>(&Bsb[cur][row * 64 + gg * 8]);
      }
    }
    #pragma unroll
    for (int kk = 0; kk < 2; ++kk)
      #pragma unroll
      for (int mm = 0; mm < 8; ++mm)
        #pragma unroll
        for (int nn = 0; nn < 8; ++nn)
          acc[mm][nn] = __builtin_amdgcn_mfma_f32_16x16x32_bf16(
              af[mm][kk], bv[nn][kk], acc[mm][nn], 0, 0, 0);
    // Tile boundary: next tile's staging must be complete in every wave.
    if (t < 3) {
      VMW(0);
      BARR();
    }
  }

  // Position-blind epilogue: 0.7*max(s,0)^2 for every element.
  float lsum = 0.0f;
  #pragma unroll
  for (int m = 0; m < 8; ++m)
    #pragma unroll
    for (int n = 0; n < 8; ++n)
      #pragma unroll
      for (int r2 = 0; r2 < 4; ++r2) {
        float u = fmaxf(acc[m][n][r2], 0.0f);
        lsum = fmaf(u, u, lsum);
      }
  lsum *= 0.7f;  // LAMBDA_NEG
  #pragma unroll
  for (int off = 1; off < 64; off <<= 1) lsum += __shfl_xor(lsum, off, 64);
  if (lane == 0) rbuf[wid] = lsum;
  __syncthreads();
  if (tid == 0) {
    atomicAdd(&slots[flat & (NSLOTS - 1)],
              rbuf[0] + rbuf[1] + rbuf[2] + rbuf[3]);
  }
}

// ---------------------------------------------------------------------------
// Kernel 3: sparse fixups, one wave per row. Diagonal: replace
// 0.7*max(s,0)^2 with (s-1)^2; each dedup'd valid semi j: replace with
// 0.7*max(0.7-s,0)^2. Same bf16 inputs + fp32 accum as the MFMA path.
// ---------------------------------------------------------------------------
__global__ __launch_bounds__(256) void corr_kernel(
    const unsigned short* __restrict__ tn,
    const unsigned short* __restrict__ vn, const int* __restrict__ sidx,
    float* __restrict__ slots) {
  int wid = threadIdx.x >> 6, lane = threadIdx.x & 63;
  int i = blockIdx.x * 4 + wid;

  u16x4 ta = reinterpret_cast<const u16x4*>(tn + (size_t)i * DDIM)[lane];
  float t0 = bf2f(ta[0]), t1 = bf2f(ta[1]), t2 = bf2f(ta[2]), t3 = bf2f(ta[3]);

  int j0 = sidx[(size_t)i * 3 + 0];
  int j1 = sidx[(size_t)i * 3 + 1];
  int j2 = sidx[(size_t)i * 3 + 2];
  bool v0 = (j0 >= 0) & (j0 < BDIM) & (j0 != i);
  bool v1 = (j1 >= 0) & (j1 < BDIM) & (j1 != i) & !(v0 & (j1 == j0));
  bool v2 = (j2 >= 0) & (j2 < BDIM) & (j2 != i) & !(v0 & (j2 == j0)) &
            !(v1 & (j2 == j1));

  float corr = 0.0f;
  {  // diagonal
    u16x4 va = reinterpret_cast<const u16x4*>(vn + (size_t)i * DDIM)[lane];
    float d = t0 * bf2f(va[0]) + t1 * bf2f(va[1]) + t2 * bf2f(va[2]) +
              t3 * bf2f(va[3]);
    #pragma unroll
    for (int off = 1; off < 64; off <<= 1) d += __shfl_xor(d, off, 64);
    float u = fmaxf(d, 0.0f);
    corr += (d - 1.0f) * (d - 1.0f) - 0.7f * u * u;
  }
  int jj[3] = {j0, j1, j2};
  bool vv[3] = {v0, v1, v2};
  #pragma unroll
  for (int k = 0; k < 3; ++k) {
    int j = vv[k] ? jj[k] : i;  // safe address; discarded if invalid
    u16x4 va = reinterpret_cast<const u16x4*>(vn + (size_t)j * DDIM)[lane];
    float d = t0 * bf2f(va[0]) + t1 * bf2f(va[1]) + t2 * bf2f(va[2]) +
              t3 * bf2f(va[3]);
    #pragma unroll
    for (int off = 1; off < 64; off <<= 1) d += __shfl_xor(d, off, 64);
    if (vv[k]) {
      float up = fmaxf(0.7f - d, 0.0f);
      float un = fmaxf(d, 0.0f);
      corr += 0.7f * (up * up - un * un);
    }
  }
  if (lane == 0) atomicAdd(&slots[i & (NSLOTS - 1)], corr);
}

// ---------------------------------------------------------------------------
// Kernel 4: sum the 512 slots -> out (plain store).
// ---------------------------------------------------------------------------
__global__ __launch_bounds__(256) void reduce_kernel(
    const float* __restrict__ slots, float* __restrict__ out) {
  __shared__ float rb[4];
  int tid = threadIdx.x;
  float s = slots[tid] + slots[tid + 256];
  #pragma unroll
  for (int off = 1; off < 64; off <<= 1) s += __shfl_xor(s, off, 64);
  if ((tid & 63) == 0) rb[tid >> 6] = s;
  __syncthreads();
  if (tid == 0) out[0] = rb[0] + rb[1] + rb[2] + rb[3];
}

extern "C" void kernel_launch(void* const* d_in, const int* in_sizes, int n_in,
                              void* d_out, int out_size, void* d_ws,
                              size_t ws_size, hipStream_t stream) {
  const float* t = (const float*)d_in[0];
  const float* v = (const float*)d_in[1];
  const int* sidx = (const int*)d_in[2];
  float* out = (float*)d_out;
  float* slots = (float*)d_ws;  // 512 floats
  unsigned short* tn = (unsigned short*)((char*)d_ws + 4096);  // 4 MB
  unsigned short* vn = tn + (size_t)BDIM * DDIM;               // 4 MB

  norm_convert_kernel<<<4096, 256, 0, stream>>>(t, v, tn, vn, slots);
  loss_kernel<<<1024, 256, 0, stream>>>(tn, vn, slots);
  corr_kernel<<<2048, 256, 0, stream>>>(tn, vn, sidx, slots);
  reduce_kernel<<<1, 256, 0, stream>>>(slots, out);
}